// Round 7
// baseline (455.408 us; speedup 1.0000x reference)
//
#include <hip/hip_runtime.h>
#include <hip/hip_bf16.h>

// ---------------------------------------------------------------------------
// MinigridPPOLSTMAgent forward, round 7: round-6 structure with the xperm
// allocation bug fixed (64 MB, true layout size) and tail-clamped GLDS issue.
//   T=128, B=256, N=32768, HID=128, NFLAT=1024, NA=7
// Pipeline:
//   P1 prep_wih   : w_ih fp32 [512][co*16+p] -> fp16 wb[512][p*64+co] (K-perm)
//   P2 prep_convw : w2/w3 -> MFMA A-fragment-ordered fp16 tables
//   K1 conv_fused : obs -> featb[N][p*64+co] fp16 (conv2/3 via MFMA)
//   K3 gemm_mfma  : xperm(fp16) = featb @ wb^T + (b_ih+b_hh), scattered into
//                   LSTM-lane order (16B chunks per lane)
//   K4 lstm       : 32 blocks x 256 thr (4 waves, 8 batch/block).
//                   x via global_load_lds 4-slot ring issued 3 steps ahead
//                   (tail-clamped so issue rate is constant), s_waitcnt
//                   vmcnt(8); h-exchange dbuf LDS + one raw s_barrier/step.
//   K5 heads      : out[N,8] = hid_fp16 @ [actor;critic].T + b
//
// xperm layout, value (t, b, gate g):
//   bb=b>>3, colL=b&7 ; gr=g>>7, u=g&127, wL=u>>5, uu=u&31, s=uu>>4,
//   row=uu&15, fqL=row>>2, rL=row&3, laneL=fqL*16+colL
//   halfoff = ((((t*32+bb)*4+wL)*4+gr)*64 + laneL)*8 + s*4 + rL
//   Size: 128*32*4*4*64*8 = 33,554,432 halves (64 MB; lane dim is 64 because
//   cols 8..15 are duplicate/unwritten — round 6 under-allocated this by 2x).
// ---------------------------------------------------------------------------

#define N_IMG   32768
#define T_LEN   128
#define B_ENV   256
#define HID     128

typedef _Float16 f16x8 __attribute__((ext_vector_type(8)));
typedef float    f32x4 __attribute__((ext_vector_type(4)));
typedef unsigned short ushort8v __attribute__((ext_vector_type(8)));
typedef unsigned short ushort4v __attribute__((ext_vector_type(4)));

__device__ __forceinline__ float sigm_(float x) { return 1.0f / (1.0f + __expf(-x)); }
__device__ __forceinline__ float tanh_(float x) { return 2.0f / (1.0f + __expf(-2.0f * x)) - 1.0f; }

__device__ __forceinline__ unsigned short f2h(float x) {
    union { _Float16 h; unsigned short u; } un; un.h = (_Float16)x;
    return un.u;
}
__device__ __forceinline__ float h2f(unsigned short u) {
    union { unsigned short u; _Float16 h; } un; un.u = u;
    return (float)un.h;
}

#define GLDS16(g, l) __builtin_amdgcn_global_load_lds( \
    (const __attribute__((address_space(1))) unsigned int*)(g), \
    (__attribute__((address_space(3))) unsigned int*)(l), 16, 0, 0)

// ---------------------------------------------------------------------------
// P1: w_ih fp32 [n][k=co*16+p] -> fp16 wb[n][k'=p*64+co]
// ---------------------------------------------------------------------------
__global__ void prep_wih(const float* __restrict__ w, unsigned short* __restrict__ wb)
{
    const int idx = blockIdx.x * 256 + threadIdx.x;   // < 524288
    const int n = idx >> 10, kk = idx & 1023;
    const int p = kk >> 6, co = kk & 63;
    wb[idx] = f2h(w[n * 1024 + co * 16 + p]);
}

// ---------------------------------------------------------------------------
// P2: conv2/conv3 weights -> MFMA A-fragment layout (fp16)
// ---------------------------------------------------------------------------
__global__ void prep_convw(const float* __restrict__ w2, const float* __restrict__ w3,
                           unsigned short* __restrict__ wb2g, unsigned short* __restrict__ wb3g)
{
    const int t = blockIdx.x * 256 + threadIdx.x;     // < 10240
    if (t < 2048) {
        const int j = t & 7, lane = (t >> 3) & 63, f = t >> 9;   // f = ky*2+ct
        const int ky = f >> 1, ct = f & 1;
        const int k = ((lane >> 4) << 3) + j, kx = k >> 4, ci = k & 15;
        wb2g[t] = f2h(w2[(ct * 16 + (lane & 15)) * 64 + ci * 4 + ky * 2 + kx]);
    } else if (t < 10240) {
        const int u = t - 2048;
        const int j = u & 7, lane = (u >> 3) & 63, f = u >> 9;   // f = ct*4+pos
        const int ct = f >> 2, pos = f & 3;
        const int ci = ((lane >> 4) << 3) + j;
        wb3g[u] = f2h(w3[(ct * 16 + (lane & 15)) * 128 + ci * 4 + pos]);
    }
}

// ---------------------------------------------------------------------------
// K1: fused conv. 16 images / block, 2048 blocks, 256 thr (4 waves).
// ---------------------------------------------------------------------------
__global__ __launch_bounds__(256, 2) void conv_fused(
    const float* __restrict__ obs,
    const float* __restrict__ w1, const float* __restrict__ b1,
    const float* __restrict__ b2, const float* __restrict__ b3,
    const unsigned short* __restrict__ wb2g,
    const unsigned short* __restrict__ wb3g,
    unsigned short* __restrict__ featb)
{
    __shared__ __align__(16) unsigned char u1[25856];
    __shared__ __align__(16) unsigned char u2[33024];
    __shared__ float w1s[192];
    __shared__ float b1s[16];

    float* s_obs = (float*)u1;                 // [img][148]
    unsigned short* c2s = (unsigned short*)u1; // [img][pix*32+ci], img stride 808
    unsigned short* c1s = (unsigned short*)u2; // [img][p*16+ci],  img stride 584
    unsigned short* c3s = (unsigned short*)u2; // [img][p*64+co],  img stride 1032

    const int tid = threadIdx.x, lane = tid & 63, wv = tid >> 6;
    const int base = blockIdx.x * 16;

    if (tid < 192) w1s[tid] = w1[tid];
    if (tid < 16)  b1s[tid] = b1[tid];
    for (int i = tid; i < 16 * 147; i += 256) {
        const int im = i / 147, r = i - im * 147;
        s_obs[im * 148 + r] = obs[(size_t)(base + im) * 147 + r];
    }
    __syncthreads();

    // ---- conv1 (fp32 VALU) ----
    {
        const int img = tid & 15;
        const float* ob = &s_obs[img * 148];
        for (int p = tid >> 4; p < 36; p += 16) {
            const int py = p / 6, px = p % 6;
            float o[12];
#pragma unroll
            for (int ky = 0; ky < 2; ky++)
#pragma unroll
                for (int kx = 0; kx < 2; kx++)
#pragma unroll
                    for (int cc = 0; cc < 3; cc++)
                        o[cc * 4 + ky * 2 + kx] = ob[((py + ky) * 7 + px + kx) * 3 + cc];
            unsigned short res[16];
#pragma unroll
            for (int ci = 0; ci < 16; ci++) {
                float a = b1s[ci];
#pragma unroll
                for (int qq = 0; qq < 12; qq++) a = fmaf(o[qq], w1s[ci * 12 + qq], a);
                res[ci] = f2h(fmaxf(a, 0.0f));
            }
            *(ushort8v*)&c1s[img * 584 + p * 16]     = *(ushort8v*)&res[0];
            *(ushort8v*)&c1s[img * 584 + p * 16 + 8] = *(ushort8v*)&res[8];
        }
    }
    __syncthreads();

    // ---- conv2 (MFMA) ----
    {
        const int ct = wv & 1, par = wv >> 1;
        const int img = lane & 15, kq = lane >> 4;
        f16x8 wA[2];
        wA[0] = *(const f16x8*)&wb2g[(0 + ct) * 512 + lane * 8];
        wA[1] = *(const f16x8*)&wb2g[(2 + ct) * 512 + lane * 8];
        const float4 b2v = *(const float4*)&b2[ct * 16 + kq * 4];
#pragma unroll 2
        for (int p = par; p < 25; p += 2) {
            const int py = p / 5, px = p % 5;
            f32x4 acc = {0.f, 0.f, 0.f, 0.f};
#pragma unroll
            for (int ky = 0; ky < 2; ky++) {
                const int pix = (py + ky) * 6 + px + (kq >> 1);
                const f16x8 bv = *(const f16x8*)&c1s[img * 584 + pix * 16 + (kq & 1) * 8];
                acc = __builtin_amdgcn_mfma_f32_16x16x32_f16(wA[ky], bv, acc, 0, 0, 0);
            }
            unsigned short r4[4];
            r4[0] = f2h(fmaxf(acc[0] + b2v.x, 0.0f));
            r4[1] = f2h(fmaxf(acc[1] + b2v.y, 0.0f));
            r4[2] = f2h(fmaxf(acc[2] + b2v.z, 0.0f));
            r4[3] = f2h(fmaxf(acc[3] + b2v.w, 0.0f));
            *(ushort4v*)&c2s[img * 808 + p * 32 + ct * 16 + kq * 4] = *(ushort4v*)&r4[0];
        }
    }
    __syncthreads();

    // ---- conv3 (MFMA) ----
    {
        const int ct = wv;
        const int img = lane & 15, kq = lane >> 4;
        f16x8 wA3[4];
#pragma unroll
        for (int pos = 0; pos < 4; pos++)
            wA3[pos] = *(const f16x8*)&wb3g[(ct * 4 + pos) * 512 + lane * 8];
        const float4 b3v = *(const float4*)&b3[ct * 16 + kq * 4];
#pragma unroll 4
        for (int p = 0; p < 16; p++) {
            const int py = p >> 2, px = p & 3;
            f32x4 acc = {0.f, 0.f, 0.f, 0.f};
#pragma unroll
            for (int pos = 0; pos < 4; pos++) {
                const int pix = (py + (pos >> 1)) * 5 + px + (pos & 1);
                const f16x8 bv = *(const f16x8*)&c2s[img * 808 + pix * 32 + kq * 8];
                acc = __builtin_amdgcn_mfma_f32_16x16x32_f16(wA3[pos], bv, acc, 0, 0, 0);
            }
            unsigned short r4[4];
            r4[0] = f2h(fmaxf(acc[0] + b3v.x, 0.0f));
            r4[1] = f2h(fmaxf(acc[1] + b3v.y, 0.0f));
            r4[2] = f2h(fmaxf(acc[2] + b3v.z, 0.0f));
            r4[3] = f2h(fmaxf(acc[3] + b3v.w, 0.0f));
            *(ushort4v*)&c3s[img * 1032 + p * 64 + ct * 16 + kq * 4] = *(ushort4v*)&r4[0];
        }
    }
    __syncthreads();

#pragma unroll
    for (int i = 0; i < 8; i++) {
        const int gi = i * 2048 + tid * 8;
        const int img = gi >> 10, flat = gi & 1023;
        *(ushort8v*)&featb[(size_t)(base + img) * 1024 + flat] =
            *(const ushort8v*)&c3s[img * 1032 + flat];
    }
}

// ---------------------------------------------------------------------------
// K3: xperm(fp16) = featb @ wb^T + bias, scattered into LSTM-lane layout.
// ---------------------------------------------------------------------------
__global__ __launch_bounds__(256, 2) void gemm_xproj_mfma(
    const unsigned short* __restrict__ A,
    const unsigned short* __restrict__ W,
    const float* __restrict__ b_ih, const float* __restrict__ b_hh,
    unsigned short* __restrict__ Xp)
{
    __shared__ unsigned short As[128 * 32];
    __shared__ unsigned short Bs[128 * 32];
    __shared__ float bsum[128];

    const int tid  = threadIdx.x;
    const int bx = blockIdx.x & 3;
    const int by = blockIdx.x >> 2;
    const int m0 = by * 128, n0 = bx * 128;
    const int lane = tid & 63, wave = tid >> 6;
    const int wm = (wave >> 1) * 64, wn = (wave & 1) * 64;
    const int srow = tid >> 2, sseg = tid & 3;

    if (tid < 128) bsum[tid] = b_ih[n0 + tid] + b_hh[n0 + tid];

    const unsigned short* Ag = A + (size_t)(m0 + srow) * 1024 + sseg * 8;
    const unsigned short* Wg = W + (size_t)(n0 + srow) * 1024 + sseg * 8;

    f32x4 acc[4][4];
#pragma unroll
    for (int i = 0; i < 4; i++)
#pragma unroll
        for (int j = 0; j < 4; j++) acc[i][j] = (f32x4){0.f, 0.f, 0.f, 0.f};

    const int fr = lane & 15, fq = lane >> 4;

    for (int k0 = 0; k0 < 1024; k0 += 32) {
        __syncthreads();
        GLDS16(Ag + k0,             (char*)As + tid * 16);
        GLDS16(Ag + k0 + 64 * 1024, (char*)As + tid * 16 + 4096);
        GLDS16(Wg + k0,             (char*)Bs + tid * 16);
        GLDS16(Wg + k0 + 64 * 1024, (char*)Bs + tid * 16 + 4096);
        __syncthreads();

        f16x8 af[4], bfv[4];
#pragma unroll
        for (int i = 0; i < 4; i++)
            af[i] = *(const f16x8*)&As[(wm + i * 16 + fr) * 32 + fq * 8];
#pragma unroll
        for (int j = 0; j < 4; j++)
            bfv[j] = *(const f16x8*)&Bs[(wn + j * 16 + fr) * 32 + fq * 8];
#pragma unroll
        for (int i = 0; i < 4; i++)
#pragma unroll
            for (int j = 0; j < 4; j++)
                acc[i][j] = __builtin_amdgcn_mfma_f32_16x16x32_f16(af[i], bfv[j], acc[i][j], 0, 0, 0);
    }

    // scatter epilogue into LSTM-lane layout (fp16, + bias)
#pragma unroll
    for (int j = 0; j < 4; j++) {
        const int n  = n0 + wn + j * 16 + fr;
        const int gr = n >> 7, u = n & 127;
        const int wL = u >> 5, uu = u & 31;
        const int sL = uu >> 4, row = uu & 15;
        const int fqL = row >> 2, rL = row & 3;
        const float bsv = bsum[n - n0];
#pragma unroll
        for (int i = 0; i < 4; i++) {
#pragma unroll
            for (int r = 0; r < 4; r++) {
                const int m = m0 + wm + i * 16 + fq * 4 + r;
                const int t = m >> 8, bidx = m & 255;
                const int bbL = bidx >> 3, colL = bidx & 7;
                const size_t off =
                    ((((size_t)(t * 32 + bbL) * 4 + wL) * 4 + gr) * 64 + fqL * 16 + colL) * 8
                    + sL * 4 + rL;
                Xp[off] = f2h(acc[i][j][r] + bsv);
            }
        }
    }
}

// ---------------------------------------------------------------------------
// K4: LSTM. 32 blocks x 256 thr (4 waves), 8 batch/block (cols 8..15 of the
//   16-wide MFMA N-dim duplicate cols 0..7 and are masked on store).
//   Wave w owns units [32w,32w+32). Per step: 8 tiles x 4 kc = 32 MFMAs.
//   x: GLDS 4-slot LDS ring, issued for t+3 EVERY step (tail-clamped source
//   keeps the vmcnt queue arithmetic valid); s_waitcnt vmcnt(8) at step top
//   guarantees GLDS(t) landed (drains everything older than the newest 8 =
//   st(t-1)x2 + GLDS(t+2)x4 + st(t-2)x2).
//   h: double-buffered LDS, one raw s_barrier/step with lgkm-only wait.
// ---------------------------------------------------------------------------
__global__ __launch_bounds__(256, 1) void lstm_kernel(
    const unsigned short* __restrict__ xperm, const float* __restrict__ done,
    const float* __restrict__ h0, const float* __restrict__ c0,
    const float* __restrict__ w_hh,
    unsigned short* __restrict__ hid, float* __restrict__ out)
{
    __shared__ __align__(16) unsigned short xring[4 * 8192];   // 64 KB
    __shared__ __align__(16) unsigned short hx[2 * 16 * 136];  // 8.5 KB
    __shared__ float done_s[T_LEN * 8];                        // 4 KB

    const int tid = threadIdx.x, l = tid & 63, w = tid >> 6;
    const int col = l & 15, q = l >> 4;
    const int bb = blockIdx.x;
    const int colc = col & 7;
    const int b = bb * 8 + colc;           // cols 8..15 duplicate, stores masked

    // stage done
    for (int i = tid; i < T_LEN * 8; i += 256)
        done_s[i] = done[(i >> 3) * B_ENV + bb * 8 + (i & 7)];

    // w_hh fragments: A[m=col][k=q*8+j], tile (gr,s): g = gr*128+32w+16s+col
    f16x8 wB[4][2][4];
#pragma unroll
    for (int gr = 0; gr < 4; gr++)
#pragma unroll
        for (int s = 0; s < 2; s++) {
            const float* wr = w_hh + (size_t)(gr * 128 + 32 * w + 16 * s + col) * 128 + q * 8;
#pragma unroll
            for (int kc = 0; kc < 4; kc++) {
                const float4 x0 = *(const float4*)&wr[kc * 32];
                const float4 x1 = *(const float4*)&wr[kc * 32 + 4];
                f16x8 f;
                f[0] = (_Float16)x0.x; f[1] = (_Float16)x0.y;
                f[2] = (_Float16)x0.z; f[3] = (_Float16)x0.w;
                f[4] = (_Float16)x1.x; f[5] = (_Float16)x1.y;
                f[6] = (_Float16)x1.z; f[7] = (_Float16)x1.w;
                wB[gr][s][kc] = f;
            }
        }

    // c state + hx[0] init (h0 masked with done[0])
    float cst[2][4];
    {
        const float d0 = done[b];
        const float m0v = 1.0f - d0;
#pragma unroll
        for (int s = 0; s < 2; s++) {
            const float4 cv = *(const float4*)&c0[(size_t)b * 128 + 32 * w + 16 * s + 4 * q];
            cst[s][0] = cv.x; cst[s][1] = cv.y; cst[s][2] = cv.z; cst[s][3] = cv.w;
            const float4 hv = *(const float4*)&h0[(size_t)b * 128 + 32 * w + 16 * s + 4 * q];
            unsigned short hh[4];
            hh[0] = f2h(hv.x * m0v); hh[1] = f2h(hv.y * m0v);
            hh[2] = f2h(hv.z * m0v); hh[3] = f2h(hv.w * m0v);
            *(ushort4v*)&hx[col * 136 + 32 * w + 16 * s + 4 * q] = *(ushort4v*)hh;
        }
    }

    // preload ring slots 0..2
#pragma unroll
    for (int s0 = 0; s0 < 3; s0++) {
#pragma unroll
        for (int gr = 0; gr < 4; gr++) {
            const unsigned short* src = xperm +
                ((((size_t)(s0 * 32 + bb) * 4 + w) * 4 + gr) * 64 + l) * 8;
            GLDS16(src, (char*)&xring[s0 * 8192] + ((w * 4 + gr) * 64 + l) * 16);
        }
    }
    __syncthreads();    // done_s, hx[0] visible; ring slots 0..2 drained (vmcnt 0)

    float dcur = done_s[colc];
    float hlast[2][4];

#pragma unroll 4
    for (int t = 0; t < T_LEN; t++) {
        // guarantee GLDS(t) (issued at t-3 or preloop) landed
        asm volatile("s_waitcnt vmcnt(8)" ::: "memory");

        // x fragments (lane-private)
        const unsigned short* xs = &xring[(t & 3) * 8192];
        ushort8v xv[4];
#pragma unroll
        for (int gr = 0; gr < 4; gr++)
            xv[gr] = *(const ushort8v*)&xs[((w * 4 + gr) * 64 + l) * 8];

        // h fragments: B[n=col][k=kc*32+q*8+j]
        const unsigned short* hb = &hx[(t & 1) * 2176];
        f16x8 hf[4];
#pragma unroll
        for (int kc = 0; kc < 4; kc++)
            hf[kc] = *(const f16x8*)&hb[col * 136 + kc * 32 + q * 8];

        // issue ring DMA for t+3 EVERY step (tail source clamped to T-1;
        // those slots are never read — keeps vmcnt counting exact)
        {
            const int tp = (t + 3 < T_LEN) ? t + 3 : T_LEN - 1;
#pragma unroll
            for (int gr = 0; gr < 4; gr++) {
                const unsigned short* src = xperm +
                    ((((size_t)(tp * 32 + bb) * 4 + w) * 4 + gr) * 64 + l) * 8;
                GLDS16(src, (char*)&xring[((t + 3) & 3) * 8192] + ((w * 4 + gr) * 64 + l) * 16);
            }
        }

        // gates: acc[gr][s] = x (bias folded in GEMM) + W.h
        f32x4 acc[4][2];
#pragma unroll
        for (int gr = 0; gr < 4; gr++)
#pragma unroll
            for (int s = 0; s < 2; s++) {
                f32x4 a;
#pragma unroll
                for (int r = 0; r < 4; r++) a[r] = h2f(xv[gr][s * 4 + r]);
                acc[gr][s] = a;
            }
#pragma unroll
        for (int kc = 0; kc < 4; kc++)
#pragma unroll
            for (int gr = 0; gr < 4; gr++)
#pragma unroll
                for (int s = 0; s < 2; s++)
                    acc[gr][s] = __builtin_amdgcn_mfma_f32_16x16x32_f16(
                        wB[gr][s][kc], hf[kc], acc[gr][s], 0, 0, 0);

        const int t1 = (t + 1 < T_LEN) ? t + 1 : t;
        const float dnext = done_s[t1 * 8 + colc];

        // activations + state update (c-mask uses done[t])
        const float mc = 1.0f - dcur;
        unsigned short hhm[2][4], hho[2][4];
        const float mh = (t < T_LEN - 1) ? (1.0f - dnext) : 1.0f;
#pragma unroll
        for (int s = 0; s < 2; s++) {
#pragma unroll
            for (int r = 0; r < 4; r++) {
                const float ig = sigm_(acc[0][s][r]);
                const float fg = sigm_(acc[1][s][r]);
                const float gg = tanh_(acc[2][s][r]);
                const float og = sigm_(acc[3][s][r]);
                const float cn = fmaf(fg, cst[s][r] * mc, ig * gg);
                cst[s][r] = cn;
                const float hv = og * tanh_(cn);
                hlast[s][r] = hv;
                hho[s][r] = f2h(hv);
                hhm[s][r] = f2h(hv * mh);
            }
        }

        // hid store (fp16, unmasked h), real cols only
        if (col < 8) {
#pragma unroll
            for (int s = 0; s < 2; s++)
                *(ushort4v*)&hid[((size_t)t * B_ENV + b) * 128 + 32 * w + 16 * s + 4 * q] =
                    *(ushort4v*)hho[s];
        }

        // h(t+1) into other buffer, premasked with done[t+1]
        unsigned short* hw = &hx[((t + 1) & 1) * 2176];
#pragma unroll
        for (int s = 0; s < 2; s++)
            *(ushort4v*)&hw[col * 136 + 32 * w + 16 * s + 4 * q] = *(ushort4v*)hhm[s];

        // one raw barrier: LDS-only wait, vmem stays in flight
        asm volatile("s_waitcnt lgkmcnt(0)" ::: "memory");
        __builtin_amdgcn_s_barrier();
        asm volatile("" ::: "memory");

        dcur = dnext;
    }

    if (col < 8) {
#pragma unroll
        for (int s = 0; s < 2; s++) {
            *(float4*)&out[262144 + (size_t)b * 128 + 32 * w + 16 * s + 4 * q] =
                make_float4(hlast[s][0], hlast[s][1], hlast[s][2], hlast[s][3]);
            *(float4*)&out[294912 + (size_t)b * 128 + 32 * w + 16 * s + 4 * q] =
                make_float4(cst[s][0], cst[s][1], cst[s][2], cst[s][3]);
        }
    }
}

// ---------------------------------------------------------------------------
// K5: heads from fp16 hid. out[n][0..6]=actor, [7]=critic. 32 rows/block.
// ---------------------------------------------------------------------------
__global__ __launch_bounds__(256, 2) void heads_kernel(
    const unsigned short* __restrict__ hid,
    const float* __restrict__ aw, const float* __restrict__ ab,
    const float* __restrict__ cw, const float* __restrict__ cb,
    float* __restrict__ out)
{
    __shared__ float hs[32 * 129];
    __shared__ float ws[8 * 130];
    __shared__ float bs[8];

    const int tid = threadIdx.x;
    const int n0 = blockIdx.x * 32;

    for (int i = tid; i < 1024; i += 256) {
        const int r = i >> 7, k = i & 127;
        ws[r * 130 + k] = (r < 7) ? aw[r * 128 + k] : cw[k];
    }
    if (tid < 8) bs[tid] = (tid < 7) ? ab[tid] : cb[0];
    for (int i = tid; i < 512; i += 256) {          // 512 ushort8 groups
        const int r = i >> 4, k8 = i & 15;
        const ushort8v v = *(const ushort8v*)&hid[(size_t)(n0 + r) * 128 + k8 * 8];
#pragma unroll
        for (int e = 0; e < 8; e++) hs[r * 129 + k8 * 8 + e] = h2f(v[e]);
    }
    __syncthreads();

    const int r = tid >> 3, jj = tid & 7;
    float acc = bs[jj];
    const float* hp = &hs[r * 129];
    const float* wp = &ws[jj * 130];
#pragma unroll
    for (int k = 0; k < 128; k++) acc = fmaf(hp[k], wp[k], acc);
    out[(size_t)(n0 + r) * 8 + jj] = acc;
}

// ---------------------------------------------------------------------------
extern "C" void kernel_launch(void* const* d_in, const int* in_sizes, int n_in,
                              void* d_out, int out_size, void* d_ws, size_t ws_size,
                              hipStream_t stream)
{
    (void)in_sizes; (void)n_in; (void)out_size; (void)ws_size;

    const float* obs  = (const float*)d_in[0];
    const float* done = (const float*)d_in[1];
    const float* h0   = (const float*)d_in[2];
    const float* c0   = (const float*)d_in[3];
    const float* w1   = (const float*)d_in[4];
    const float* b1   = (const float*)d_in[5];
    const float* w2   = (const float*)d_in[6];
    const float* b2   = (const float*)d_in[7];
    const float* w3   = (const float*)d_in[8];
    const float* b3   = (const float*)d_in[9];
    const float* w_ih = (const float*)d_in[10];
    const float* w_hh = (const float*)d_in[11];
    const float* b_ih = (const float*)d_in[12];
    const float* b_hh = (const float*)d_in[13];
    const float* aw   = (const float*)d_in[14];
    const float* ab   = (const float*)d_in[15];
    const float* cw   = (const float*)d_in[16];
    const float* cb   = (const float*)d_in[17];
    float* out = (float*)d_out;

    unsigned short* featb = (unsigned short*)d_ws;     // 33,554,432 u16 (64 MB)
    unsigned short* wb    = featb + 33554432ull;       //    524,288 u16
    unsigned short* wb2g  = wb    + 524288ull;         //      2,048 u16
    unsigned short* wb3g  = wb2g  + 2048ull;           //      8,192 u16
    unsigned short* xperm = wb3g  + 8192ull;           // 33,554,432 u16 (64 MB) — true layout size
    unsigned short* hid   = xperm + 33554432ull;       //  4,194,304 u16 (8 MB)
    // total = 71,837,696 u16 = 143.7 MB (< 152 MB proven available in round 2)

    prep_wih<<<2048, 256, 0, stream>>>(w_ih, wb);
    prep_convw<<<40, 256, 0, stream>>>(w2, w3, wb2g, wb3g);
    conv_fused<<<2048, 256, 0, stream>>>(obs, w1, b1, b2, b3, wb2g, wb3g, featb);
    gemm_xproj_mfma<<<1024, 256, 0, stream>>>(featb, wb, b_ih, b_hh, xperm);
    lstm_kernel<<<32, 256, 0, stream>>>(xperm, done, h0, c0, w_hh, hid, out);
    heads_kernel<<<1024, 256, 0, stream>>>(hid, aw, ab, cw, cb, out);
}

// Round 8
// 424.883 us; speedup vs baseline: 1.0718x; 1.0718x over previous
//
#include <hip/hip_runtime.h>
#include <hip/hip_bf16.h>

// ---------------------------------------------------------------------------
// MinigridPPOLSTMAgent forward, round 8: compiler-invisible LDS in LSTM loop.
//   T=128, B=256, N=32768, HID=128, NFLAT=1024, NA=7
// Key change vs r7: ALL in-loop LDS traffic in the LSTM is inline asm
// (ds_read/ds_write), so the memory legalizer cannot insert vmcnt(0) drains
// between global_load_lds and the reads. Waits are manual: vmcnt(6) at step
// top (3-step-deep 2-GLDS+1-store pipeline), lgkmcnt(0) tied to the read regs.
// 16 blocks x 512 thr (8 waves), 16 real batch/block (no lane duplication;
// xperm halves to 32 MB). Wave w2 owns units [16*w2,16*w2+16).
//
// xperm layout, value (t, b, gate g):
//   bb=b>>4, colL=b&15 ; gr=g>>7, w2=(g>>4)&7, uu=g&15, qL=uu>>2, rL=uu&3,
//   grp=gr>>1, gi=gr&1
//   half = ((((t*16+bb)*8+w2)*2+grp)*64 + qL*16+colL)*8 + gi*4 + rL
//   => wave w2's 2 GLDS chunks (grp) are 64 lanes x 16B contiguous.
//   Size: 128*16*8*2*64*8 = 16,777,216 halves = 32 MB.
// ---------------------------------------------------------------------------

#define N_IMG   32768
#define T_LEN   128
#define B_ENV   256
#define HID     128

typedef _Float16 f16x8 __attribute__((ext_vector_type(8)));
typedef float    f32x4 __attribute__((ext_vector_type(4)));
typedef int      i32x4 __attribute__((ext_vector_type(4)));
typedef int      i32x2 __attribute__((ext_vector_type(2)));
typedef unsigned short ushort8v __attribute__((ext_vector_type(8)));
typedef unsigned short ushort4v __attribute__((ext_vector_type(4)));

__device__ __forceinline__ float sigm_(float x) { return 1.0f / (1.0f + __expf(-x)); }
__device__ __forceinline__ float tanh_(float x) { return 2.0f / (1.0f + __expf(-2.0f * x)) - 1.0f; }

__device__ __forceinline__ unsigned short f2h(float x) {
    union { _Float16 h; unsigned short u; } un; un.h = (_Float16)x;
    return un.u;
}
__device__ __forceinline__ float h2f(unsigned short u) {
    union { unsigned short u; _Float16 h; } un; un.u = u;
    return (float)un.h;
}
__device__ __forceinline__ unsigned lds_off(void* p) {
    return (unsigned)(size_t)(__attribute__((address_space(3))) char*)(p);
}

#define GLDS16(g, l) __builtin_amdgcn_global_load_lds( \
    (const __attribute__((address_space(1))) unsigned int*)(g), \
    (__attribute__((address_space(3))) unsigned int*)(l), 16, 0, 0)

// ---------------------------------------------------------------------------
// P1: w_ih fp32 [n][k=co*16+p] -> fp16 wb[n][k'=p*64+co]
// ---------------------------------------------------------------------------
__global__ void prep_wih(const float* __restrict__ w, unsigned short* __restrict__ wb)
{
    const int idx = blockIdx.x * 256 + threadIdx.x;   // < 524288
    const int n = idx >> 10, kk = idx & 1023;
    const int p = kk >> 6, co = kk & 63;
    wb[idx] = f2h(w[n * 1024 + co * 16 + p]);
}

// ---------------------------------------------------------------------------
// P2: conv2/conv3 weights -> MFMA A-fragment layout (fp16)
// ---------------------------------------------------------------------------
__global__ void prep_convw(const float* __restrict__ w2, const float* __restrict__ w3,
                           unsigned short* __restrict__ wb2g, unsigned short* __restrict__ wb3g)
{
    const int t = blockIdx.x * 256 + threadIdx.x;     // < 10240
    if (t < 2048) {
        const int j = t & 7, lane = (t >> 3) & 63, f = t >> 9;   // f = ky*2+ct
        const int ky = f >> 1, ct = f & 1;
        const int k = ((lane >> 4) << 3) + j, kx = k >> 4, ci = k & 15;
        wb2g[t] = f2h(w2[(ct * 16 + (lane & 15)) * 64 + ci * 4 + ky * 2 + kx]);
    } else if (t < 10240) {
        const int u = t - 2048;
        const int j = u & 7, lane = (u >> 3) & 63, f = u >> 9;   // f = ct*4+pos
        const int ct = f >> 2, pos = f & 3;
        const int ci = ((lane >> 4) << 3) + j;
        wb3g[u] = f2h(w3[(ct * 16 + (lane & 15)) * 128 + ci * 4 + pos]);
    }
}

// ---------------------------------------------------------------------------
// K1: fused conv. 16 images / block, 2048 blocks, 256 thr (4 waves).
// ---------------------------------------------------------------------------
__global__ __launch_bounds__(256, 2) void conv_fused(
    const float* __restrict__ obs,
    const float* __restrict__ w1, const float* __restrict__ b1,
    const float* __restrict__ b2, const float* __restrict__ b3,
    const unsigned short* __restrict__ wb2g,
    const unsigned short* __restrict__ wb3g,
    unsigned short* __restrict__ featb)
{
    __shared__ __align__(16) unsigned char u1[25856];
    __shared__ __align__(16) unsigned char u2[33024];
    __shared__ float w1s[192];
    __shared__ float b1s[16];

    float* s_obs = (float*)u1;                 // [img][148]
    unsigned short* c2s = (unsigned short*)u1; // [img][pix*32+ci], img stride 808
    unsigned short* c1s = (unsigned short*)u2; // [img][p*16+ci],  img stride 584
    unsigned short* c3s = (unsigned short*)u2; // [img][p*64+co],  img stride 1032

    const int tid = threadIdx.x, lane = tid & 63, wv = tid >> 6;
    const int base = blockIdx.x * 16;

    if (tid < 192) w1s[tid] = w1[tid];
    if (tid < 16)  b1s[tid] = b1[tid];
    for (int i = tid; i < 16 * 147; i += 256) {
        const int im = i / 147, r = i - im * 147;
        s_obs[im * 148 + r] = obs[(size_t)(base + im) * 147 + r];
    }
    __syncthreads();

    // ---- conv1 (fp32 VALU) ----
    {
        const int img = tid & 15;
        const float* ob = &s_obs[img * 148];
        for (int p = tid >> 4; p < 36; p += 16) {
            const int py = p / 6, px = p % 6;
            float o[12];
#pragma unroll
            for (int ky = 0; ky < 2; ky++)
#pragma unroll
                for (int kx = 0; kx < 2; kx++)
#pragma unroll
                    for (int cc = 0; cc < 3; cc++)
                        o[cc * 4 + ky * 2 + kx] = ob[((py + ky) * 7 + px + kx) * 3 + cc];
            unsigned short res[16];
#pragma unroll
            for (int ci = 0; ci < 16; ci++) {
                float a = b1s[ci];
#pragma unroll
                for (int qq = 0; qq < 12; qq++) a = fmaf(o[qq], w1s[ci * 12 + qq], a);
                res[ci] = f2h(fmaxf(a, 0.0f));
            }
            *(ushort8v*)&c1s[img * 584 + p * 16]     = *(ushort8v*)&res[0];
            *(ushort8v*)&c1s[img * 584 + p * 16 + 8] = *(ushort8v*)&res[8];
        }
    }
    __syncthreads();

    // ---- conv2 (MFMA) ----
    {
        const int ct = wv & 1, par = wv >> 1;
        const int img = lane & 15, kq = lane >> 4;
        f16x8 wA[2];
        wA[0] = *(const f16x8*)&wb2g[(0 + ct) * 512 + lane * 8];
        wA[1] = *(const f16x8*)&wb2g[(2 + ct) * 512 + lane * 8];
        const float4 b2v = *(const float4*)&b2[ct * 16 + kq * 4];
#pragma unroll 2
        for (int p = par; p < 25; p += 2) {
            const int py = p / 5, px = p % 5;
            f32x4 acc = {0.f, 0.f, 0.f, 0.f};
#pragma unroll
            for (int ky = 0; ky < 2; ky++) {
                const int pix = (py + ky) * 6 + px + (kq >> 1);
                const f16x8 bv = *(const f16x8*)&c1s[img * 584 + pix * 16 + (kq & 1) * 8];
                acc = __builtin_amdgcn_mfma_f32_16x16x32_f16(wA[ky], bv, acc, 0, 0, 0);
            }
            unsigned short r4[4];
            r4[0] = f2h(fmaxf(acc[0] + b2v.x, 0.0f));
            r4[1] = f2h(fmaxf(acc[1] + b2v.y, 0.0f));
            r4[2] = f2h(fmaxf(acc[2] + b2v.z, 0.0f));
            r4[3] = f2h(fmaxf(acc[3] + b2v.w, 0.0f));
            *(ushort4v*)&c2s[img * 808 + p * 32 + ct * 16 + kq * 4] = *(ushort4v*)&r4[0];
        }
    }
    __syncthreads();

    // ---- conv3 (MFMA) ----
    {
        const int ct = wv;
        const int img = lane & 15, kq = lane >> 4;
        f16x8 wA3[4];
#pragma unroll
        for (int pos = 0; pos < 4; pos++)
            wA3[pos] = *(const f16x8*)&wb3g[(ct * 4 + pos) * 512 + lane * 8];
        const float4 b3v = *(const float4*)&b3[ct * 16 + kq * 4];
#pragma unroll 4
        for (int p = 0; p < 16; p++) {
            const int py = p >> 2, px = p & 3;
            f32x4 acc = {0.f, 0.f, 0.f, 0.f};
#pragma unroll
            for (int pos = 0; pos < 4; pos++) {
                const int pix = (py + (pos >> 1)) * 5 + px + (pos & 1);
                const f16x8 bv = *(const f16x8*)&c2s[img * 808 + pix * 32 + kq * 8];
                acc = __builtin_amdgcn_mfma_f32_16x16x32_f16(wA3[pos], bv, acc, 0, 0, 0);
            }
            unsigned short r4[4];
            r4[0] = f2h(fmaxf(acc[0] + b3v.x, 0.0f));
            r4[1] = f2h(fmaxf(acc[1] + b3v.y, 0.0f));
            r4[2] = f2h(fmaxf(acc[2] + b3v.z, 0.0f));
            r4[3] = f2h(fmaxf(acc[3] + b3v.w, 0.0f));
            *(ushort4v*)&c3s[img * 1032 + p * 64 + ct * 16 + kq * 4] = *(ushort4v*)&r4[0];
        }
    }
    __syncthreads();

#pragma unroll
    for (int i = 0; i < 8; i++) {
        const int gi = i * 2048 + tid * 8;
        const int img = gi >> 10, flat = gi & 1023;
        *(ushort8v*)&featb[(size_t)(base + img) * 1024 + flat] =
            *(const ushort8v*)&c3s[img * 1032 + flat];
    }
}

// ---------------------------------------------------------------------------
// K3: xperm(fp16) = featb @ wb^T + bias, scattered into LSTM-lane layout v3.
// ---------------------------------------------------------------------------
__global__ __launch_bounds__(256, 2) void gemm_xproj_mfma(
    const unsigned short* __restrict__ A,
    const unsigned short* __restrict__ W,
    const float* __restrict__ b_ih, const float* __restrict__ b_hh,
    unsigned short* __restrict__ Xp)
{
    __shared__ unsigned short As[128 * 32];
    __shared__ unsigned short Bs[128 * 32];
    __shared__ float bsum[128];

    const int tid  = threadIdx.x;
    const int bx = blockIdx.x & 3;
    const int by = blockIdx.x >> 2;
    const int m0 = by * 128, n0 = bx * 128;
    const int lane = tid & 63, wave = tid >> 6;
    const int wm = (wave >> 1) * 64, wn = (wave & 1) * 64;
    const int srow = tid >> 2, sseg = tid & 3;

    if (tid < 128) bsum[tid] = b_ih[n0 + tid] + b_hh[n0 + tid];

    const unsigned short* Ag = A + (size_t)(m0 + srow) * 1024 + sseg * 8;
    const unsigned short* Wg = W + (size_t)(n0 + srow) * 1024 + sseg * 8;

    f32x4 acc[4][4];
#pragma unroll
    for (int i = 0; i < 4; i++)
#pragma unroll
        for (int j = 0; j < 4; j++) acc[i][j] = (f32x4){0.f, 0.f, 0.f, 0.f};

    const int fr = lane & 15, fq = lane >> 4;

    for (int k0 = 0; k0 < 1024; k0 += 32) {
        __syncthreads();
        GLDS16(Ag + k0,             (char*)As + tid * 16);
        GLDS16(Ag + k0 + 64 * 1024, (char*)As + tid * 16 + 4096);
        GLDS16(Wg + k0,             (char*)Bs + tid * 16);
        GLDS16(Wg + k0 + 64 * 1024, (char*)Bs + tid * 16 + 4096);
        __syncthreads();

        f16x8 af[4], bfv[4];
#pragma unroll
        for (int i = 0; i < 4; i++)
            af[i] = *(const f16x8*)&As[(wm + i * 16 + fr) * 32 + fq * 8];
#pragma unroll
        for (int j = 0; j < 4; j++)
            bfv[j] = *(const f16x8*)&Bs[(wn + j * 16 + fr) * 32 + fq * 8];
#pragma unroll
        for (int i = 0; i < 4; i++)
#pragma unroll
            for (int j = 0; j < 4; j++)
                acc[i][j] = __builtin_amdgcn_mfma_f32_16x16x32_f16(af[i], bfv[j], acc[i][j], 0, 0, 0);
    }

    // scatter epilogue into LSTM-lane layout v3 (fp16, + bias)
#pragma unroll
    for (int j = 0; j < 4; j++) {
        const int n  = n0 + wn + j * 16 + fr;
        const int gr = n >> 7, w2 = (n >> 4) & 7, uu = n & 15;
        const int qL = uu >> 2, rL = uu & 3;
        const int grp = gr >> 1, gi = gr & 1;
        const float bsv = bsum[n - n0];
#pragma unroll
        for (int i = 0; i < 4; i++) {
#pragma unroll
            for (int r = 0; r < 4; r++) {
                const int m = m0 + wm + i * 16 + fq * 4 + r;
                const int t = m >> 8, bidx = m & 255;
                const int bbL = bidx >> 4, colL = bidx & 15;
                const size_t off =
                    ((((size_t)(t * 16 + bbL) * 8 + w2) * 2 + grp) * 64 + qL * 16 + colL) * 8
                    + gi * 4 + rL;
                Xp[off] = f2h(acc[i][j][r] + bsv);
            }
        }
    }
}

// ---------------------------------------------------------------------------
// K4: LSTM, compiler-invisible LDS loop. 16 blocks x 512 thr (8 waves),
//   16 real batch/block. Wave w2 owns units [16*w2,16*w2+16); lane: col=l&15
//   (batch), q=l>>4, units u0=16*w2+4q..+3. Per step: 4 gr-tiles x 4 kc = 16
//   MFMAs; 2 GLDS (x, 16B/lane) + 1 hid store (8B) = 3 vmem ops/step.
//   vmcnt(6) at step top <=> GLDS issued 3 steps ago landed. All in-loop LDS
//   reads/writes are volatile inline asm (no legalizer vmcnt drains), with a
//   register-tied lgkmcnt(0) before use and lgkm(0)+s_barrier at step end.
// ---------------------------------------------------------------------------
__global__ __launch_bounds__(512, 2) void lstm_kernel(
    const unsigned short* __restrict__ xperm, const float* __restrict__ done,
    const float* __restrict__ h0, const float* __restrict__ c0,
    const float* __restrict__ w_hh,
    unsigned short* __restrict__ hid, float* __restrict__ out)
{
    __shared__ __align__(16) unsigned short xring[4 * 8192];  // 4 slots x 16KB
    __shared__ __align__(16) unsigned short hx[2 * 2176];     // h dbuf, col stride 136
    __shared__ float done_s[T_LEN * 16];                      // 8 KB

    const int tid = threadIdx.x, l = tid & 63, w2 = tid >> 6;  // 8 waves
    const int col = l & 15, q = l >> 4;
    const int bb = blockIdx.x;
    const int b  = bb * 16 + col;
    const int u0 = 16 * w2 + 4 * q;

    // stage done (compiler-visible, pre-loop only)
    for (int i = tid; i < T_LEN * 16; i += 512)
        done_s[i] = done[(i >> 4) * B_ENV + bb * 16 + (i & 15)];

    // w_hh fragments: A[m=col][k=q*8+j], tile gr: g = gr*128 + 16*w2 + col
    f16x8 wB[4][4];
#pragma unroll
    for (int gr = 0; gr < 4; gr++) {
        const float* wr = w_hh + (size_t)(gr * 128 + 16 * w2 + col) * 128 + q * 8;
#pragma unroll
        for (int kc = 0; kc < 4; kc++) {
            const float4 x0 = *(const float4*)&wr[kc * 32];
            const float4 x1 = *(const float4*)&wr[kc * 32 + 4];
            f16x8 f;
            f[0] = (_Float16)x0.x; f[1] = (_Float16)x0.y;
            f[2] = (_Float16)x0.z; f[3] = (_Float16)x0.w;
            f[4] = (_Float16)x1.x; f[5] = (_Float16)x1.y;
            f[6] = (_Float16)x1.z; f[7] = (_Float16)x1.w;
            wB[gr][kc] = f;
        }
    }

    // state init (h0 masked with done[0] into hx[0])
    float cst[4], hlast[4];
    const float d0 = done[b];
    {
        const float m0v = 1.0f - d0;
        const float4 cv = *(const float4*)&c0[(size_t)b * 128 + u0];
        cst[0] = cv.x; cst[1] = cv.y; cst[2] = cv.z; cst[3] = cv.w;
        const float4 hv = *(const float4*)&h0[(size_t)b * 128 + u0];
        hlast[0] = hv.x; hlast[1] = hv.y; hlast[2] = hv.z; hlast[3] = hv.w;
        unsigned short hh[4];
        hh[0] = f2h(hv.x * m0v); hh[1] = f2h(hv.y * m0v);
        hh[2] = f2h(hv.z * m0v); hh[3] = f2h(hv.w * m0v);
        *(ushort4v*)&hx[col * 136 + u0] = *(ushort4v*)hh;
    }

    // preload ring slots 0..2 (2 GLDS each)
#pragma unroll
    for (int s0 = 0; s0 < 3; s0++) {
#pragma unroll
        for (int grp = 0; grp < 2; grp++) {
            const unsigned short* src = xperm +
                ((((size_t)(s0 * 16 + bb) * 8 + w2) * 2 + grp) * 64 + l) * 8;
            GLDS16(src, (char*)xring + (s0 << 14) + ((w2 * 2 + grp) * 64 + l) * 16);
        }
    }
    __syncthreads();   // drains vmcnt(0): slots 0..2 + done_s/hx visible

    const unsigned xbase  = lds_off(xring)  + ((w2 * 2) * 64 + l) * 16;
    const unsigned hbase  = lds_off(hx)     + col * 272 + q * 16;
    const unsigned hwbase = lds_off(hx)     + col * 272 + u0 * 2;
    const unsigned dbase  = lds_off(done_s) + col * 4;

    float dcur = d0;

#pragma unroll 1
    for (int t = 0; t < T_LEN; t++) {
        // GLDS issued at t-3 has landed when <=6 newer vmem ops outstanding
        asm volatile("s_waitcnt vmcnt(6)" ::: "memory");

        const unsigned xa = xbase + ((t & 3) << 14);
        const unsigned ha = hbase + (t & 1) * 4352;
        const int t1 = (t + 1 < T_LEN) ? t + 1 : t;
        const unsigned da = dbase + (unsigned)t1 * 64;

        i32x4 x0, x1, hr0, hr1, hr2, hr3; int dnx;
        asm volatile("ds_read_b128 %0, %2 offset:0\n\t"
                     "ds_read_b128 %1, %2 offset:1024"
                     : "=&v"(x0), "=&v"(x1) : "v"(xa) : "memory");
        asm volatile("ds_read_b128 %0, %4 offset:0\n\t"
                     "ds_read_b128 %1, %4 offset:64\n\t"
                     "ds_read_b128 %2, %4 offset:128\n\t"
                     "ds_read_b128 %3, %4 offset:192"
                     : "=&v"(hr0), "=&v"(hr1), "=&v"(hr2), "=&v"(hr3)
                     : "v"(ha) : "memory");
        asm volatile("ds_read_b32 %0, %1" : "=&v"(dnx) : "v"(da) : "memory");
        asm volatile("s_waitcnt lgkmcnt(0)"
                     : "+v"(x0), "+v"(x1), "+v"(hr0), "+v"(hr1), "+v"(hr2), "+v"(hr3), "+v"(dnx)
                     :: "memory");

        // issue ring DMA for t+3 (tail-clamped: uniform 2 GLDS/step)
        {
            const int tp = (t + 3 < T_LEN) ? t + 3 : T_LEN - 1;
#pragma unroll
            for (int grp = 0; grp < 2; grp++) {
                const unsigned short* src = xperm +
                    ((((size_t)(tp * 16 + bb) * 8 + w2) * 2 + grp) * 64 + l) * 8;
                GLDS16(src, (char*)xring + ((tp & 3) << 14) + ((w2 * 2 + grp) * 64 + l) * 16);
            }
        }

        // fragments
        union UH { i32x4 i; f16x8 v; _Float16 e[8]; };
        UH uh0, uh1, uh2, uh3, ux0, ux1;
        uh0.i = hr0; uh1.i = hr1; uh2.i = hr2; uh3.i = hr3;
        ux0.i = x0;  ux1.i = x1;

        f32x4 acc[4];
#pragma unroll
        for (int r = 0; r < 4; r++) {
            acc[0][r] = (float)ux0.e[r];
            acc[1][r] = (float)ux0.e[4 + r];
            acc[2][r] = (float)ux1.e[r];
            acc[3][r] = (float)ux1.e[4 + r];
        }
        acc[0] = __builtin_amdgcn_mfma_f32_16x16x32_f16(wB[0][0], uh0.v, acc[0], 0, 0, 0);
        acc[1] = __builtin_amdgcn_mfma_f32_16x16x32_f16(wB[1][0], uh0.v, acc[1], 0, 0, 0);
        acc[2] = __builtin_amdgcn_mfma_f32_16x16x32_f16(wB[2][0], uh0.v, acc[2], 0, 0, 0);
        acc[3] = __builtin_amdgcn_mfma_f32_16x16x32_f16(wB[3][0], uh0.v, acc[3], 0, 0, 0);
        acc[0] = __builtin_amdgcn_mfma_f32_16x16x32_f16(wB[0][1], uh1.v, acc[0], 0, 0, 0);
        acc[1] = __builtin_amdgcn_mfma_f32_16x16x32_f16(wB[1][1], uh1.v, acc[1], 0, 0, 0);
        acc[2] = __builtin_amdgcn_mfma_f32_16x16x32_f16(wB[2][1], uh1.v, acc[2], 0, 0, 0);
        acc[3] = __builtin_amdgcn_mfma_f32_16x16x32_f16(wB[3][1], uh1.v, acc[3], 0, 0, 0);
        acc[0] = __builtin_amdgcn_mfma_f32_16x16x32_f16(wB[0][2], uh2.v, acc[0], 0, 0, 0);
        acc[1] = __builtin_amdgcn_mfma_f32_16x16x32_f16(wB[1][2], uh2.v, acc[1], 0, 0, 0);
        acc[2] = __builtin_amdgcn_mfma_f32_16x16x32_f16(wB[2][2], uh2.v, acc[2], 0, 0, 0);
        acc[3] = __builtin_amdgcn_mfma_f32_16x16x32_f16(wB[3][2], uh2.v, acc[3], 0, 0, 0);
        acc[0] = __builtin_amdgcn_mfma_f32_16x16x32_f16(wB[0][3], uh3.v, acc[0], 0, 0, 0);
        acc[1] = __builtin_amdgcn_mfma_f32_16x16x32_f16(wB[1][3], uh3.v, acc[1], 0, 0, 0);
        acc[2] = __builtin_amdgcn_mfma_f32_16x16x32_f16(wB[2][3], uh3.v, acc[2], 0, 0, 0);
        acc[3] = __builtin_amdgcn_mfma_f32_16x16x32_f16(wB[3][3], uh3.v, acc[3], 0, 0, 0);

        union DF { int i; float f; } df; df.i = dnx;
        const float dnext = df.f;
        const float mc = 1.0f - dcur;
        const float mh = (t < T_LEN - 1) ? (1.0f - dnext) : 1.0f;

        unsigned short hho[4], hhm[4];
#pragma unroll
        for (int r = 0; r < 4; r++) {
            const float ig = sigm_(acc[0][r]);
            const float fg = sigm_(acc[1][r]);
            const float gg = tanh_(acc[2][r]);
            const float og = sigm_(acc[3][r]);
            const float cn = fmaf(fg, cst[r] * mc, ig * gg);
            cst[r] = cn;
            const float hv = og * tanh_(cn);
            hlast[r] = hv;
            hho[r] = f2h(hv);
            hhm[r] = f2h(hv * mh);
        }

        // hid store (1 x 8B global store; fire-and-forget)
        *(ushort4v*)&hid[((size_t)t * B_ENV + b) * 128 + u0] = *(ushort4v*)hho;

        // h(t+1) into other buffer (asm ds_write_b64, premasked with done[t+1])
        {
            union HM { ushort4v u; i32x2 i; } hm; hm.u = *(ushort4v*)hhm;
            const unsigned hwa = hwbase + ((t + 1) & 1) * 4352;
            asm volatile("ds_write_b64 %0, %1" :: "v"(hwa), "v"(hm.i) : "memory");
        }

        // one raw barrier: LDS-only wait; vmem (GLDS + hid stores) stays in flight
        asm volatile("s_waitcnt lgkmcnt(0)\n\ts_barrier" ::: "memory");

        dcur = dnext;
    }

    *(float4*)&out[262144 + (size_t)b * 128 + u0] =
        make_float4(hlast[0], hlast[1], hlast[2], hlast[3]);
    *(float4*)&out[294912 + (size_t)b * 128 + u0] =
        make_float4(cst[0], cst[1], cst[2], cst[3]);
}

// ---------------------------------------------------------------------------
// K5: heads from fp16 hid. out[n][0..6]=actor, [7]=critic. 32 rows/block.
// ---------------------------------------------------------------------------
__global__ __launch_bounds__(256, 2) void heads_kernel(
    const unsigned short* __restrict__ hid,
    const float* __restrict__ aw, const float* __restrict__ ab,
    const float* __restrict__ cw, const float* __restrict__ cb,
    float* __restrict__ out)
{
    __shared__ float hs[32 * 129];
    __shared__ float ws[8 * 130];
    __shared__ float bs[8];

    const int tid = threadIdx.x;
    const int n0 = blockIdx.x * 32;

    for (int i = tid; i < 1024; i += 256) {
        const int r = i >> 7, k = i & 127;
        ws[r * 130 + k] = (r < 7) ? aw[r * 128 + k] : cw[k];
    }
    if (tid < 8) bs[tid] = (tid < 7) ? ab[tid] : cb[0];
    for (int i = tid; i < 512; i += 256) {
        const int r = i >> 4, k8 = i & 15;
        const ushort8v v = *(const ushort8v*)&hid[(size_t)(n0 + r) * 128 + k8 * 8];
#pragma unroll
        for (int e = 0; e < 8; e++) hs[r * 129 + k8 * 8 + e] = h2f(v[e]);
    }
    __syncthreads();

    const int r = tid >> 3, jj = tid & 7;
    float acc = bs[jj];
    const float* hp = &hs[r * 129];
    const float* wp = &ws[jj * 130];
#pragma unroll
    for (int k = 0; k < 128; k++) acc = fmaf(hp[k], wp[k], acc);
    out[(size_t)(n0 + r) * 8 + jj] = acc;
}

// ---------------------------------------------------------------------------
extern "C" void kernel_launch(void* const* d_in, const int* in_sizes, int n_in,
                              void* d_out, int out_size, void* d_ws, size_t ws_size,
                              hipStream_t stream)
{
    (void)in_sizes; (void)n_in; (void)out_size; (void)ws_size;

    const float* obs  = (const float*)d_in[0];
    const float* done = (const float*)d_in[1];
    const float* h0   = (const float*)d_in[2];
    const float* c0   = (const float*)d_in[3];
    const float* w1   = (const float*)d_in[4];
    const float* b1   = (const float*)d_in[5];
    const float* w2   = (const float*)d_in[6];
    const float* b2   = (const float*)d_in[7];
    const float* w3   = (const float*)d_in[8];
    const float* b3   = (const float*)d_in[9];
    const float* w_ih = (const float*)d_in[10];
    const float* w_hh = (const float*)d_in[11];
    const float* b_ih = (const float*)d_in[12];
    const float* b_hh = (const float*)d_in[13];
    const float* aw   = (const float*)d_in[14];
    const float* ab   = (const float*)d_in[15];
    const float* cw   = (const float*)d_in[16];
    const float* cb   = (const float*)d_in[17];
    float* out = (float*)d_out;

    unsigned short* featb = (unsigned short*)d_ws;     // 33,554,432 u16 (64 MB)
    unsigned short* wb    = featb + 33554432ull;       //    524,288 u16
    unsigned short* wb2g  = wb    + 524288ull;         //      2,048 u16
    unsigned short* wb3g  = wb2g  + 2048ull;           //      8,192 u16
    unsigned short* xperm = wb3g  + 8192ull;           // 16,777,216 u16 (32 MB)
    unsigned short* hid   = xperm + 16777216ull;       //  4,194,304 u16 (8 MB)
    // total ~110 MB

    prep_wih<<<2048, 256, 0, stream>>>(w_ih, wb);
    prep_convw<<<40, 256, 0, stream>>>(w2, w3, wb2g, wb3g);
    conv_fused<<<2048, 256, 0, stream>>>(obs, w1, b1, b2, b3, wb2g, wb3g, featb);
    gemm_xproj_mfma<<<1024, 256, 0, stream>>>(featb, wb, b_ih, b_hh, xperm);
    lstm_kernel<<<16, 512, 0, stream>>>(xperm, done, h0, c0, w_hh, hid, out);
    heads_kernel<<<1024, 256, 0, stream>>>(hid, aw, ab, cw, cb, out);
}